// Round 1
// baseline (1013.655 us; speedup 1.0000x reference)
//
#include <hip/hip_runtime.h>

#define N_NODES 100000
#define N_EDGES 3200000
#define E_TOT   (N_EDGES + N_NODES)   // 3,300,000
#define F_IN    128
#define H_DIM   32
#define B_GR    256
#define NEG     0.2f

// ---- monotonic float<->uint encoding for atomicMax on floats ----
__device__ __forceinline__ unsigned fenc(float f) {
    unsigned u = __float_as_uint(f);
    return (u & 0x80000000u) ? ~u : (u | 0x80000000u);
}
__device__ __forceinline__ float fdec(unsigned u) {
    return (u & 0x80000000u) ? __uint_as_float(u & 0x7FFFFFFFu)
                             : __uint_as_float(~u);
}

// K1: xl = x@Wl, xr = x@Wr.  8 nodes/block, thread=(node_local, h)
__global__ __launch_bounds__(256) void k_linear(
    const float* __restrict__ x, const float* __restrict__ Wl,
    const float* __restrict__ Wr, float* __restrict__ xl, float* __restrict__ xr)
{
    __shared__ float Wls[F_IN * H_DIM];
    __shared__ float Wrs[F_IN * H_DIM];
    __shared__ float xs[8 * F_IN];
    int t = threadIdx.x;
    for (int i = t; i < F_IN * H_DIM; i += 256) { Wls[i] = Wl[i]; Wrs[i] = Wr[i]; }
    size_t base = (size_t)blockIdx.x * 8;
    const float4* xg = (const float4*)(x + base * F_IN);
    ((float4*)xs)[t] = xg[t];              // 1024 floats = 256 * float4
    __syncthreads();
    int nl = t >> 5, h = t & 31;
    float accl = 0.f, accr = 0.f;
    #pragma unroll 16
    for (int f = 0; f < F_IN; ++f) {
        float xv = xs[nl * F_IN + f];
        accl = fmaf(xv, Wls[f * H_DIM + h], accl);
        accr = fmaf(xv, Wrs[f * H_DIM + h], accr);
    }
    size_t n = base + nl;
    xl[n * H_DIM + h] = accl;
    xr[n * H_DIM + h] = accr;
}

// K2: per-edge GATv2 score e = att . leakyrelu(xl[s]+xr[d]); running max into mu[d]
__global__ __launch_bounds__(256) void k_edge_score(
    const int* __restrict__ ei, const float* __restrict__ xl,
    const float* __restrict__ xr, const float* __restrict__ att,
    float* __restrict__ ebuf, unsigned* __restrict__ mu)
{
    int gt = blockIdx.x * 256 + threadIdx.x;
    int i = gt >> 5, h = gt & 31;
    int s, d;
    if (i < N_EDGES) { s = ei[i]; d = ei[N_EDGES + i]; }
    else             { s = d = i - N_EDGES; }
    float v = xl[(size_t)s * H_DIM + h] + xr[(size_t)d * H_DIM + h];
    v = (v > 0.f) ? v : NEG * v;
    v *= att[h];
    v += __shfl_xor(v, 16);
    v += __shfl_xor(v, 8);
    v += __shfl_xor(v, 4);
    v += __shfl_xor(v, 2);
    v += __shfl_xor(v, 1);
    if (h == 0) {
        ebuf[i] = v;
        atomicMax(&mu[d], fenc(v));
    }
}

// K3: p = exp(e - m[d]); z[d] += p; acc[d][h] += p * xl[s][h]
__global__ __launch_bounds__(256) void k_edge_scatter(
    const int* __restrict__ ei, const float* __restrict__ xl,
    const float* __restrict__ ebuf, const unsigned* __restrict__ mu,
    float* __restrict__ z, float* __restrict__ acc)
{
    int gt = blockIdx.x * 256 + threadIdx.x;
    int i = gt >> 5, h = gt & 31;
    int s, d;
    if (i < N_EDGES) { s = ei[i]; d = ei[N_EDGES + i]; }
    else             { s = d = i - N_EDGES; }
    float p = __expf(ebuf[i] - fdec(mu[d]));
    if (h == 0) atomicAdd(&z[d], p);
    atomicAdd(&acc[(size_t)d * H_DIM + h], p * xl[(size_t)s * H_DIM + h]);
}

// K4: node_out = acc/z + bias; graph max-pool via encoded atomicMax
__global__ __launch_bounds__(256) void k_node_pool(
    const float* __restrict__ acc, const float* __restrict__ z,
    const float* __restrict__ bias, const int* __restrict__ batch,
    unsigned* __restrict__ gu)
{
    int gt = blockIdx.x * 256 + threadIdx.x;
    int n = gt >> 5, h = gt & 31;
    float v = acc[(size_t)n * H_DIM + h] / z[n] + bias[h];
    atomicMax(&gu[batch[n] * H_DIM + h], fenc(v));
}

// K5: h1 = relu(g @ W1 + b1), one block per graph
__global__ __launch_bounds__(256) void k_mlp1(
    const unsigned* __restrict__ gu, const float* __restrict__ W1,
    const float* __restrict__ b1, float* __restrict__ h1)
{
    __shared__ float gs[H_DIM];
    int b = blockIdx.x, t = threadIdx.x;
    if (t < H_DIM) gs[t] = fdec(gu[b * H_DIM + t]);
    __syncthreads();
    for (int jj = 0; jj < 4; ++jj) {
        int j = jj * 256 + t;
        float a = b1[j];
        #pragma unroll
        for (int k = 0; k < H_DIM; ++k) a = fmaf(gs[k], W1[k * 1024 + j], a);
        h1[(size_t)b * 1024 + j] = fmaxf(a, 0.f);
    }
}

// K6: h2 = relu(h1 @ W2 + b2), 4 graphs per block (W2 reuse x4)
__global__ __launch_bounds__(512) void k_mlp2(
    const float* __restrict__ h1, const float* __restrict__ W2,
    const float* __restrict__ b2, float* __restrict__ h2)
{
    __shared__ float hs[4][1024];
    int b0 = blockIdx.x * 4, t = threadIdx.x;
    for (int r = 0; r < 4; ++r)
        for (int k = t; k < 1024; k += 512) hs[r][k] = h1[(size_t)(b0 + r) * 1024 + k];
    __syncthreads();
    float bb = b2[t];
    float a0 = bb, a1 = bb, a2 = bb, a3 = bb;
    for (int k = 0; k < 1024; ++k) {
        float w = W2[(size_t)k * 512 + t];
        a0 = fmaf(hs[0][k], w, a0);
        a1 = fmaf(hs[1][k], w, a1);
        a2 = fmaf(hs[2][k], w, a2);
        a3 = fmaf(hs[3][k], w, a3);
    }
    h2[(size_t)(b0 + 0) * 512 + t] = fmaxf(a0, 0.f);
    h2[(size_t)(b0 + 1) * 512 + t] = fmaxf(a1, 0.f);
    h2[(size_t)(b0 + 2) * 512 + t] = fmaxf(a2, 0.f);
    h2[(size_t)(b0 + 3) * 512 + t] = fmaxf(a3, 0.f);
}

// K7: out = h2 @ W3 + b3, one block per graph, 4 waves (one per class)
__global__ __launch_bounds__(256) void k_mlp3(
    const float* __restrict__ h2, const float* __restrict__ W3,
    const float* __restrict__ b3, float* __restrict__ out)
{
    int b = blockIdx.x, t = threadIdx.x;
    int c = t >> 6, lane = t & 63;
    float a = 0.f;
    for (int k = lane; k < 512; k += 64)
        a = fmaf(h2[(size_t)b * 512 + k], W3[k * 4 + c], a);
    for (int off = 32; off; off >>= 1) a += __shfl_down(a, off);
    if (lane == 0) out[b * 4 + c] = a + b3[c];
}

extern "C" void kernel_launch(void* const* d_in, const int* in_sizes, int n_in,
                              void* d_out, int out_size, void* d_ws, size_t ws_size,
                              hipStream_t stream)
{
    const float* x     = (const float*)d_in[0];
    const int*   ei    = (const int*)d_in[1];
    const int*   batch = (const int*)d_in[2];
    const float* Wl    = (const float*)d_in[3];
    const float* Wr    = (const float*)d_in[4];
    const float* att   = (const float*)d_in[5];
    const float* bias  = (const float*)d_in[6];
    const float* W1    = (const float*)d_in[7];
    const float* b1    = (const float*)d_in[8];
    const float* W2    = (const float*)d_in[9];
    const float* b2    = (const float*)d_in[10];
    const float* W3    = (const float*)d_in[11];
    const float* b3    = (const float*)d_in[12];
    float* out = (float*)d_out;

    // workspace layout
    float*    xl  = (float*)d_ws;
    float*    xr  = xl + (size_t)N_NODES * H_DIM;
    float*    eb  = xr + (size_t)N_NODES * H_DIM;
    float*    z   = eb + (size_t)E_TOT;            // ---- init region start ----
    unsigned* mu  = (unsigned*)(z + N_NODES);
    float*    acc = (float*)(mu + N_NODES);
    unsigned* gu  = (unsigned*)(acc + (size_t)N_NODES * H_DIM);
    float*    h1  = (float*)(gu + B_GR * H_DIM);   // ---- init region end ----
    float*    h2  = h1 + (size_t)B_GR * 1024;

    // zero z, mu, acc, gu in one memset (mu=0 encodes -inf; gu=0 encodes -inf)
    size_t init_bytes = ((size_t)N_NODES * 2 + (size_t)N_NODES * H_DIM
                         + (size_t)B_GR * H_DIM) * sizeof(float);
    hipMemsetAsync(z, 0, init_bytes, stream);

    k_linear<<<N_NODES / 8, 256, 0, stream>>>(x, Wl, Wr, xl, xr);
    k_edge_score<<<(size_t)E_TOT * 32 / 256, 256, 0, stream>>>(ei, xl, xr, att, eb, mu);
    k_edge_scatter<<<(size_t)E_TOT * 32 / 256, 256, 0, stream>>>(ei, xl, eb, mu, z, acc);
    k_node_pool<<<N_NODES * 32 / 256, 256, 0, stream>>>(acc, z, bias, batch, gu);
    k_mlp1<<<B_GR, 256, 0, stream>>>(gu, W1, b1, h1);
    k_mlp2<<<B_GR / 4, 512, 0, stream>>>(h1, W2, b2, h2);
    k_mlp3<<<B_GR, 256, 0, stream>>>(h2, W3, b3, out);
}

// Round 2
// 781.739 us; speedup vs baseline: 1.2967x; 1.2967x over previous
//
#include <hip/hip_runtime.h>

#define N_NODES 100000
#define N_EDGES 3200000
#define F_IN    128
#define H_DIM   32
#define B_GR    256
#define NEG     0.2f

#define SCAN_TILE 1024
#define SCAN_NBLK ((N_NODES + SCAN_TILE - 1) / SCAN_TILE)   // 98

// ---- monotonic float<->uint encoding for atomicMax on floats ----
__device__ __forceinline__ unsigned fenc(float f) {
    unsigned u = __float_as_uint(f);
    return (u & 0x80000000u) ? ~u : (u | 0x80000000u);
}
__device__ __forceinline__ float fdec(unsigned u) {
    return (u & 0x80000000u) ? __uint_as_float(u & 0x7FFFFFFFu)
                             : __uint_as_float(~u);
}

// K1: xl = x@Wl, xr = x@Wr.  8 nodes/block, thread=(node_local, h)
__global__ __launch_bounds__(256) void k_linear(
    const float* __restrict__ x, const float* __restrict__ Wl,
    const float* __restrict__ Wr, float* __restrict__ xl, float* __restrict__ xr)
{
    __shared__ float Wls[F_IN * H_DIM];
    __shared__ float Wrs[F_IN * H_DIM];
    __shared__ float xs[8 * F_IN];
    int t = threadIdx.x;
    for (int i = t; i < F_IN * H_DIM; i += 256) { Wls[i] = Wl[i]; Wrs[i] = Wr[i]; }
    size_t base = (size_t)blockIdx.x * 8;
    const float4* xg = (const float4*)(x + base * F_IN);
    ((float4*)xs)[t] = xg[t];
    __syncthreads();
    int nl = t >> 5, h = t & 31;
    float accl = 0.f, accr = 0.f;
    #pragma unroll 16
    for (int f = 0; f < F_IN; ++f) {
        float xv = xs[nl * F_IN + f];
        accl = fmaf(xv, Wls[f * H_DIM + h], accl);
        accr = fmaf(xv, Wrs[f * H_DIM + h], accr);
    }
    size_t n = base + nl;
    xl[n * H_DIM + h] = accl;
    xr[n * H_DIM + h] = accr;
}

// K2: histogram of dst
__global__ __launch_bounds__(256) void k_hist(
    const int* __restrict__ dst, int* __restrict__ cnt)
{
    int i = blockIdx.x * 256 + threadIdx.x;          // group of 4 edges
    int4 d = ((const int4*)dst)[i];
    atomicAdd(&cnt[d.x], 1); atomicAdd(&cnt[d.y], 1);
    atomicAdd(&cnt[d.z], 1); atomicAdd(&cnt[d.w], 1);
}

// K3a: per-tile exclusive scan (tile = 1024, 4 elems/thread)
__global__ __launch_bounds__(256) void k_scan_a(
    const int* __restrict__ cnt, int* __restrict__ part, int* __restrict__ bsum)
{
    __shared__ int s[256];
    int b = blockIdx.x, t = threadIdx.x;
    int base = b * SCAN_TILE + t * 4;
    int v[4], sum = 0;
    #pragma unroll
    for (int i = 0; i < 4; ++i) {
        int idx = base + i;
        v[i] = (idx < N_NODES) ? cnt[idx] : 0;
        sum += v[i];
    }
    s[t] = sum; __syncthreads();
    for (int off = 1; off < 256; off <<= 1) {
        int x = (t >= off) ? s[t - off] : 0;
        __syncthreads();
        s[t] += x;
        __syncthreads();
    }
    int run = (t > 0) ? s[t - 1] : 0;
    #pragma unroll
    for (int i = 0; i < 4; ++i) {
        int idx = base + i;
        if (idx < N_NODES) part[idx] = run;
        run += v[i];
    }
    if (t == 255) bsum[b] = s[255];
}

// K3b: scan the 98 block sums (exclusive, in place), single block
__global__ __launch_bounds__(128) void k_scan_b(int* __restrict__ bsum)
{
    __shared__ int s[128];
    int t = threadIdx.x;
    s[t] = (t < SCAN_NBLK) ? bsum[t] : 0; __syncthreads();
    for (int off = 1; off < 128; off <<= 1) {
        int x = (t >= off) ? s[t - off] : 0;
        __syncthreads();
        s[t] += x;
        __syncthreads();
    }
    if (t < SCAN_NBLK) bsum[t] = (t > 0) ? s[t - 1] : 0;
}

// K3c: combine, write rowstart + cursor
__global__ __launch_bounds__(256) void k_scan_c(
    const int* __restrict__ part, const int* __restrict__ bsum,
    int* __restrict__ rowstart, int* __restrict__ cursor)
{
    int i = blockIdx.x * 256 + threadIdx.x;
    if (i < N_NODES) {
        int v = part[i] + bsum[i >> 10];
        rowstart[i] = v;
        cursor[i] = v;
    }
    if (i == 0) rowstart[N_NODES] = N_EDGES;
}

// K4: scatter src ids into dst-sorted CSR
__global__ __launch_bounds__(256) void k_build(
    const int* __restrict__ ei, int* __restrict__ cursor, int* __restrict__ srt)
{
    int i = blockIdx.x * 256 + threadIdx.x;          // group of 4 edges
    int4 s = ((const int4*)ei)[i];
    int4 d = ((const int4*)(ei + N_EDGES))[i];
    int p;
    p = atomicAdd(&cursor[d.x], 1); srt[p] = s.x;
    p = atomicAdd(&cursor[d.y], 1); srt[p] = s.y;
    p = atomicAdd(&cursor[d.z], 1); srt[p] = s.z;
    p = atomicAdd(&cursor[d.w], 1); srt[p] = s.w;
}

// K5: fused score + online softmax + aggregate + bias + graph max-pool.
// One wave per node: lanes 0-31 take even edges, 32-63 odd edges; h = lane&31.
__global__ __launch_bounds__(256) void k_aggregate(
    const int* __restrict__ rowstart, const int* __restrict__ srt,
    const float* __restrict__ xl, const float* __restrict__ xr,
    const float* __restrict__ att, const float* __restrict__ bias,
    const int* __restrict__ batch, unsigned* __restrict__ gu)
{
    int gt = blockIdx.x * 256 + threadIdx.x;
    int n = gt >> 6;
    int lane = threadIdx.x & 63;
    int h = lane & 31, hi = lane >> 5;

    float a   = att[h];
    float xrv = xr[(size_t)n * H_DIM + h];
    float xlv = xl[(size_t)n * H_DIM + h];

    float m, z, acc;
    if (hi == 0) {   // self-loop goes to half 0
        float v = xlv + xrv;
        v = (v > 0.f) ? v : NEG * v;
        float t = v * a;
        t += __shfl_xor(t, 16); t += __shfl_xor(t, 8);
        t += __shfl_xor(t, 4);  t += __shfl_xor(t, 2); t += __shfl_xor(t, 1);
        m = t; z = 1.f; acc = xlv;
    } else {
        m = -1e30f; z = 0.f; acc = 0.f;
    }

    int e0 = rowstart[n], e1 = rowstart[n + 1];
    for (int j = e0 + hi; j < e1; j += 2) {
        int s = srt[j];
        float xs = xl[(size_t)s * H_DIM + h];
        float v = xs + xrv;
        v = (v > 0.f) ? v : NEG * v;
        float t = v * a;
        t += __shfl_xor(t, 16); t += __shfl_xor(t, 8);
        t += __shfl_xor(t, 4);  t += __shfl_xor(t, 2); t += __shfl_xor(t, 1);
        float mn = fmaxf(m, t);
        float sc = __expf(m - mn), p = __expf(t - mn);
        z = fmaf(z, sc, p);
        acc = fmaf(acc, sc, p * xs);
        m = mn;
    }

    // merge the two halves
    float mo = __shfl_xor(m, 32), zo = __shfl_xor(z, 32), ao = __shfl_xor(acc, 32);
    float mn = fmaxf(m, mo);
    float s0 = __expf(m - mn), s1 = __expf(mo - mn);
    z = z * s0 + zo * s1;
    acc = acc * s0 + ao * s1;

    float outv = acc / z + bias[h];
    if (hi == 0) atomicMax(&gu[batch[n] * H_DIM + h], fenc(outv));
}

// K6: h1 = relu(g @ W1 + b1)
__global__ __launch_bounds__(256) void k_mlp1(
    const unsigned* __restrict__ gu, const float* __restrict__ W1,
    const float* __restrict__ b1, float* __restrict__ h1)
{
    __shared__ float gs[H_DIM];
    int b = blockIdx.x, t = threadIdx.x;
    if (t < H_DIM) gs[t] = fdec(gu[b * H_DIM + t]);
    __syncthreads();
    for (int jj = 0; jj < 4; ++jj) {
        int j = jj * 256 + t;
        float a = b1[j];
        #pragma unroll
        for (int k = 0; k < H_DIM; ++k) a = fmaf(gs[k], W1[k * 1024 + j], a);
        h1[(size_t)b * 1024 + j] = fmaxf(a, 0.f);
    }
}

// K7: h2 = relu(h1 @ W2 + b2), 4 graphs per block
__global__ __launch_bounds__(512) void k_mlp2(
    const float* __restrict__ h1, const float* __restrict__ W2,
    const float* __restrict__ b2, float* __restrict__ h2)
{
    __shared__ float hs[4][1024];
    int b0 = blockIdx.x * 4, t = threadIdx.x;
    for (int r = 0; r < 4; ++r)
        for (int k = t; k < 1024; k += 512) hs[r][k] = h1[(size_t)(b0 + r) * 1024 + k];
    __syncthreads();
    float bb = b2[t];
    float a0 = bb, a1 = bb, a2 = bb, a3 = bb;
    for (int k = 0; k < 1024; ++k) {
        float w = W2[(size_t)k * 512 + t];
        a0 = fmaf(hs[0][k], w, a0);
        a1 = fmaf(hs[1][k], w, a1);
        a2 = fmaf(hs[2][k], w, a2);
        a3 = fmaf(hs[3][k], w, a3);
    }
    h2[(size_t)(b0 + 0) * 512 + t] = fmaxf(a0, 0.f);
    h2[(size_t)(b0 + 1) * 512 + t] = fmaxf(a1, 0.f);
    h2[(size_t)(b0 + 2) * 512 + t] = fmaxf(a2, 0.f);
    h2[(size_t)(b0 + 3) * 512 + t] = fmaxf(a3, 0.f);
}

// K8: out = h2 @ W3 + b3
__global__ __launch_bounds__(256) void k_mlp3(
    const float* __restrict__ h2, const float* __restrict__ W3,
    const float* __restrict__ b3, float* __restrict__ out)
{
    int b = blockIdx.x, t = threadIdx.x;
    int c = t >> 6, lane = t & 63;
    float a = 0.f;
    for (int k = lane; k < 512; k += 64)
        a = fmaf(h2[(size_t)b * 512 + k], W3[k * 4 + c], a);
    for (int off = 32; off; off >>= 1) a += __shfl_down(a, off);
    if (lane == 0) out[b * 4 + c] = a + b3[c];
}

extern "C" void kernel_launch(void* const* d_in, const int* in_sizes, int n_in,
                              void* d_out, int out_size, void* d_ws, size_t ws_size,
                              hipStream_t stream)
{
    const float* x     = (const float*)d_in[0];
    const int*   ei    = (const int*)d_in[1];
    const int*   batch = (const int*)d_in[2];
    const float* Wl    = (const float*)d_in[3];
    const float* Wr    = (const float*)d_in[4];
    const float* att   = (const float*)d_in[5];
    const float* bias  = (const float*)d_in[6];
    const float* W1    = (const float*)d_in[7];
    const float* b1    = (const float*)d_in[8];
    const float* W2    = (const float*)d_in[9];
    const float* b2    = (const float*)d_in[10];
    const float* W3    = (const float*)d_in[11];
    const float* b3    = (const float*)d_in[12];
    float* out = (float*)d_out;

    // workspace layout
    float*    xl       = (float*)d_ws;
    float*    xr       = xl + (size_t)N_NODES * H_DIM;
    int*      srt      = (int*)(xr + (size_t)N_NODES * H_DIM);
    int*      rowstart = srt + N_EDGES;
    int*      cursor   = rowstart + N_NODES + 1;
    int*      part     = cursor + N_NODES;
    int*      bsum     = part + N_NODES;
    int*      cnt      = bsum + 128;              // ---- zeroed region start ----
    unsigned* gu       = (unsigned*)(cnt + N_NODES);
    float*    h1       = (float*)(gu + B_GR * H_DIM);  // ---- zeroed region end ----
    float*    h2       = h1 + (size_t)B_GR * 1024;

    hipMemsetAsync(cnt, 0, (size_t)(N_NODES + B_GR * H_DIM) * sizeof(int), stream);

    k_linear<<<N_NODES / 8, 256, 0, stream>>>(x, Wl, Wr, xl, xr);
    k_hist  <<<N_EDGES / 4 / 256, 256, 0, stream>>>(ei + N_EDGES, cnt);
    k_scan_a<<<SCAN_NBLK, 256, 0, stream>>>(cnt, part, bsum);
    k_scan_b<<<1, 128, 0, stream>>>(bsum);
    k_scan_c<<<(N_NODES + 255) / 256, 256, 0, stream>>>(part, bsum, rowstart, cursor);
    k_build <<<N_EDGES / 4 / 256, 256, 0, stream>>>(ei, cursor, srt);
    k_aggregate<<<(size_t)N_NODES * 64 / 256, 256, 0, stream>>>(
        rowstart, srt, xl, xr, att, bias, batch, gu);
    k_mlp1<<<B_GR, 256, 0, stream>>>(gu, W1, b1, h1);
    k_mlp2<<<B_GR / 4, 512, 0, stream>>>(h1, W2, b2, h2);
    k_mlp3<<<B_GR, 256, 0, stream>>>(h2, W3, b3, out);
}

// Round 3
// 602.812 us; speedup vs baseline: 1.6815x; 1.2968x over previous
//
#include <hip/hip_runtime.h>

#define N_NODES 100000
#define N_EDGES 3200000
#define F_IN    128
#define H_DIM   32
#define B_GR    256
#define NEG     0.2f

#define SCAN_TILE 1024
#define SCAN_NBLK ((N_NODES + SCAN_TILE - 1) / SCAN_TILE)   // 98

#define N_BIN     8
#define BIN_SZ    (N_NODES / N_BIN)      // 12500 nodes per bin
#define BUILD_NBLK (N_EDGES / 1024)      // 3125 blocks per pass (4 edges/thread)

// ---- monotonic float<->uint encoding for atomicMax on floats ----
__device__ __forceinline__ unsigned fenc(float f) {
    unsigned u = __float_as_uint(f);
    return (u & 0x80000000u) ? ~u : (u | 0x80000000u);
}
__device__ __forceinline__ float fdec(unsigned u) {
    return (u & 0x80000000u) ? __uint_as_float(u & 0x7FFFFFFFu)
                             : __uint_as_float(~u);
}

// K1: xl = x@Wl, xr = x@Wr.  8 nodes/block, thread=(node_local, h)
__global__ __launch_bounds__(256) void k_linear(
    const float* __restrict__ x, const float* __restrict__ Wl,
    const float* __restrict__ Wr, float* __restrict__ xl, float* __restrict__ xr)
{
    __shared__ float Wls[F_IN * H_DIM];
    __shared__ float Wrs[F_IN * H_DIM];
    __shared__ float xs[8 * F_IN];
    int t = threadIdx.x;
    for (int i = t; i < F_IN * H_DIM; i += 256) { Wls[i] = Wl[i]; Wrs[i] = Wr[i]; }
    size_t base = (size_t)blockIdx.x * 8;
    const float4* xg = (const float4*)(x + base * F_IN);
    ((float4*)xs)[t] = xg[t];
    __syncthreads();
    int nl = t >> 5, h = t & 31;
    float accl = 0.f, accr = 0.f;
    #pragma unroll 16
    for (int f = 0; f < F_IN; ++f) {
        float xv = xs[nl * F_IN + f];
        accl = fmaf(xv, Wls[f * H_DIM + h], accl);
        accr = fmaf(xv, Wrs[f * H_DIM + h], accr);
    }
    size_t n = base + nl;
    xl[n * H_DIM + h] = accl;
    xr[n * H_DIM + h] = accr;
}

// K2: histogram of dst
__global__ __launch_bounds__(256) void k_hist(
    const int* __restrict__ dst, int* __restrict__ cnt)
{
    int i = blockIdx.x * 256 + threadIdx.x;          // group of 4 edges
    int4 d = ((const int4*)dst)[i];
    atomicAdd(&cnt[d.x], 1); atomicAdd(&cnt[d.y], 1);
    atomicAdd(&cnt[d.z], 1); atomicAdd(&cnt[d.w], 1);
}

// K3a: per-tile exclusive scan (tile = 1024, 4 elems/thread)
__global__ __launch_bounds__(256) void k_scan_a(
    const int* __restrict__ cnt, int* __restrict__ part, int* __restrict__ bsum)
{
    __shared__ int s[256];
    int b = blockIdx.x, t = threadIdx.x;
    int base = b * SCAN_TILE + t * 4;
    int v[4], sum = 0;
    #pragma unroll
    for (int i = 0; i < 4; ++i) {
        int idx = base + i;
        v[i] = (idx < N_NODES) ? cnt[idx] : 0;
        sum += v[i];
    }
    s[t] = sum; __syncthreads();
    for (int off = 1; off < 256; off <<= 1) {
        int x = (t >= off) ? s[t - off] : 0;
        __syncthreads();
        s[t] += x;
        __syncthreads();
    }
    int run = (t > 0) ? s[t - 1] : 0;
    #pragma unroll
    for (int i = 0; i < 4; ++i) {
        int idx = base + i;
        if (idx < N_NODES) part[idx] = run;
        run += v[i];
    }
    if (t == 255) bsum[b] = s[255];
}

// K3b: scan the 98 block sums (exclusive, in place), single block
__global__ __launch_bounds__(128) void k_scan_b(int* __restrict__ bsum)
{
    __shared__ int s[128];
    int t = threadIdx.x;
    s[t] = (t < SCAN_NBLK) ? bsum[t] : 0; __syncthreads();
    for (int off = 1; off < 128; off <<= 1) {
        int x = (t >= off) ? s[t - off] : 0;
        __syncthreads();
        s[t] += x;
        __syncthreads();
    }
    if (t < SCAN_NBLK) bsum[t] = (t > 0) ? s[t - 1] : 0;
}

// K3c: combine, write rowstart + cursor
__global__ __launch_bounds__(256) void k_scan_c(
    const int* __restrict__ part, const int* __restrict__ bsum,
    int* __restrict__ rowstart, int* __restrict__ cursor)
{
    int i = blockIdx.x * 256 + threadIdx.x;
    if (i < N_NODES) {
        int v = part[i] + bsum[i >> 10];
        rowstart[i] = v;
        cursor[i] = v;
    }
    if (i == 0) rowstart[N_NODES] = N_EDGES;
}

// K4: binned scatter of src ids into dst-sorted CSR.
// 8 passes over the (L3-resident) edge list; each pass only scatters into a
// ~1.6 MB window of srt -> window stays L2-resident, full lines accumulate.
__global__ __launch_bounds__(256) void k_build(
    const int* __restrict__ ei, int* __restrict__ cursor, int* __restrict__ srt)
{
    int pass = blockIdx.x / BUILD_NBLK;
    int blk  = blockIdx.x % BUILD_NBLK;
    int lo = pass * BIN_SZ, hi = lo + BIN_SZ;
    int i = blk * 256 + threadIdx.x;                 // group of 4 edges
    int4 s = ((const int4*)ei)[i];
    int4 d = ((const int4*)(ei + N_EDGES))[i];
    if (d.x >= lo && d.x < hi) { int p = atomicAdd(&cursor[d.x], 1); srt[p] = s.x; }
    if (d.y >= lo && d.y < hi) { int p = atomicAdd(&cursor[d.y], 1); srt[p] = s.y; }
    if (d.z >= lo && d.z < hi) { int p = atomicAdd(&cursor[d.z], 1); srt[p] = s.z; }
    if (d.w >= lo && d.w < hi) { int p = atomicAdd(&cursor[d.w], 1); srt[p] = s.w; }
}

// K5: fused score + online softmax + aggregate + bias + graph max-pool.
// One wave per node: lanes 0-31 even edges, 32-63 odd edges; h = lane&31.
// 2-edge unroll per half to overlap the shfl-reduce chains.
__global__ __launch_bounds__(256) void k_aggregate(
    const int* __restrict__ rowstart, const int* __restrict__ srt,
    const float* __restrict__ xl, const float* __restrict__ xr,
    const float* __restrict__ att, const float* __restrict__ bias,
    const int* __restrict__ batch, unsigned* __restrict__ gu)
{
    int gt = blockIdx.x * 256 + threadIdx.x;
    int n = gt >> 6;
    int lane = threadIdx.x & 63;
    int h = lane & 31, half = lane >> 5;

    float a   = att[h];
    float xrv = xr[(size_t)n * H_DIM + h];
    float xlv = xl[(size_t)n * H_DIM + h];

    float m, z, acc;
    if (half == 0) {   // self-loop goes to half 0
        float v = xlv + xrv;
        v = (v > 0.f) ? v : NEG * v;
        float t = v * a;
        t += __shfl_xor(t, 16); t += __shfl_xor(t, 8);
        t += __shfl_xor(t, 4);  t += __shfl_xor(t, 2); t += __shfl_xor(t, 1);
        m = t; z = 1.f; acc = xlv;
    } else {
        m = -1e30f; z = 0.f; acc = 0.f;
    }

    int e0 = rowstart[n], e1 = rowstart[n + 1];
    int j = e0 + half;
    for (; j + 2 < e1; j += 4) {
        int s0 = srt[j], s1 = srt[j + 2];
        float xs0 = xl[(size_t)s0 * H_DIM + h];
        float xs1 = xl[(size_t)s1 * H_DIM + h];
        float v0 = xs0 + xrv; v0 = (v0 > 0.f) ? v0 : NEG * v0;
        float v1 = xs1 + xrv; v1 = (v1 > 0.f) ? v1 : NEG * v1;
        float t0 = v0 * a, t1 = v1 * a;
        t0 += __shfl_xor(t0, 16); t1 += __shfl_xor(t1, 16);
        t0 += __shfl_xor(t0, 8);  t1 += __shfl_xor(t1, 8);
        t0 += __shfl_xor(t0, 4);  t1 += __shfl_xor(t1, 4);
        t0 += __shfl_xor(t0, 2);  t1 += __shfl_xor(t1, 2);
        t0 += __shfl_xor(t0, 1);  t1 += __shfl_xor(t1, 1);
        float mn = fmaxf(m, fmaxf(t0, t1));
        float sc = __expf(m - mn);
        float p0 = __expf(t0 - mn), p1 = __expf(t1 - mn);
        z = fmaf(z, sc, p0 + p1);
        acc = fmaf(acc, sc, fmaf(p0, xs0, p1 * xs1));
        m = mn;
    }
    for (; j < e1; j += 2) {
        int s = srt[j];
        float xs = xl[(size_t)s * H_DIM + h];
        float v = xs + xrv;
        v = (v > 0.f) ? v : NEG * v;
        float t = v * a;
        t += __shfl_xor(t, 16); t += __shfl_xor(t, 8);
        t += __shfl_xor(t, 4);  t += __shfl_xor(t, 2); t += __shfl_xor(t, 1);
        float mn = fmaxf(m, t);
        float sc = __expf(m - mn), p = __expf(t - mn);
        z = fmaf(z, sc, p);
        acc = fmaf(acc, sc, p * xs);
        m = mn;
    }

    // merge the two halves
    float mo = __shfl_xor(m, 32), zo = __shfl_xor(z, 32), ao = __shfl_xor(acc, 32);
    float mn2 = fmaxf(m, mo);
    float s0 = __expf(m - mn2), s1 = __expf(mo - mn2);
    z = z * s0 + zo * s1;
    acc = acc * s0 + ao * s1;

    float outv = acc / z + bias[h];
    if (half == 0) atomicMax(&gu[batch[n] * H_DIM + h], fenc(outv));
}

// K6: h1 = relu(g @ W1 + b1)
__global__ __launch_bounds__(256) void k_mlp1(
    const unsigned* __restrict__ gu, const float* __restrict__ W1,
    const float* __restrict__ b1, float* __restrict__ h1)
{
    __shared__ float gs[H_DIM];
    int b = blockIdx.x, t = threadIdx.x;
    if (t < H_DIM) gs[t] = fdec(gu[b * H_DIM + t]);
    __syncthreads();
    for (int jj = 0; jj < 4; ++jj) {
        int j = jj * 256 + t;
        float a = b1[j];
        #pragma unroll
        for (int k = 0; k < H_DIM; ++k) a = fmaf(gs[k], W1[k * 1024 + j], a);
        h1[(size_t)b * 1024 + j] = fmaxf(a, 0.f);
    }
}

// K7: h2 = relu(h1 @ W2 + b2), 4 graphs per block
__global__ __launch_bounds__(512) void k_mlp2(
    const float* __restrict__ h1, const float* __restrict__ W2,
    const float* __restrict__ b2, float* __restrict__ h2)
{
    __shared__ float hs[4][1024];
    int b0 = blockIdx.x * 4, t = threadIdx.x;
    for (int r = 0; r < 4; ++r)
        for (int k = t; k < 1024; k += 512) hs[r][k] = h1[(size_t)(b0 + r) * 1024 + k];
    __syncthreads();
    float bb = b2[t];
    float a0 = bb, a1 = bb, a2 = bb, a3 = bb;
    for (int k = 0; k < 1024; ++k) {
        float w = W2[(size_t)k * 512 + t];
        a0 = fmaf(hs[0][k], w, a0);
        a1 = fmaf(hs[1][k], w, a1);
        a2 = fmaf(hs[2][k], w, a2);
        a3 = fmaf(hs[3][k], w, a3);
    }
    h2[(size_t)(b0 + 0) * 512 + t] = fmaxf(a0, 0.f);
    h2[(size_t)(b0 + 1) * 512 + t] = fmaxf(a1, 0.f);
    h2[(size_t)(b0 + 2) * 512 + t] = fmaxf(a2, 0.f);
    h2[(size_t)(b0 + 3) * 512 + t] = fmaxf(a3, 0.f);
}

// K8: out = h2 @ W3 + b3
__global__ __launch_bounds__(256) void k_mlp3(
    const float* __restrict__ h2, const float* __restrict__ W3,
    const float* __restrict__ b3, float* __restrict__ out)
{
    int b = blockIdx.x, t = threadIdx.x;
    int c = t >> 6, lane = t & 63;
    float a = 0.f;
    for (int k = lane; k < 512; k += 64)
        a = fmaf(h2[(size_t)b * 512 + k], W3[k * 4 + c], a);
    for (int off = 32; off; off >>= 1) a += __shfl_down(a, off);
    if (lane == 0) out[b * 4 + c] = a + b3[c];
}

extern "C" void kernel_launch(void* const* d_in, const int* in_sizes, int n_in,
                              void* d_out, int out_size, void* d_ws, size_t ws_size,
                              hipStream_t stream)
{
    const float* x     = (const float*)d_in[0];
    const int*   ei    = (const int*)d_in[1];
    const int*   batch = (const int*)d_in[2];
    const float* Wl    = (const float*)d_in[3];
    const float* Wr    = (const float*)d_in[4];
    const float* att   = (const float*)d_in[5];
    const float* bias  = (const float*)d_in[6];
    const float* W1    = (const float*)d_in[7];
    const float* b1    = (const float*)d_in[8];
    const float* W2    = (const float*)d_in[9];
    const float* b2    = (const float*)d_in[10];
    const float* W3    = (const float*)d_in[11];
    const float* b3    = (const float*)d_in[12];
    float* out = (float*)d_out;

    // workspace layout
    float*    xl       = (float*)d_ws;
    float*    xr       = xl + (size_t)N_NODES * H_DIM;
    int*      srt      = (int*)(xr + (size_t)N_NODES * H_DIM);
    int*      rowstart = srt + N_EDGES;
    int*      cursor   = rowstart + N_NODES + 1;
    int*      part     = cursor + N_NODES;
    int*      bsum     = part + N_NODES;
    int*      cnt      = bsum + 128;              // ---- zeroed region start ----
    unsigned* gu       = (unsigned*)(cnt + N_NODES);
    float*    h1       = (float*)(gu + B_GR * H_DIM);  // ---- zeroed region end ----
    float*    h2       = h1 + (size_t)B_GR * 1024;

    hipMemsetAsync(cnt, 0, (size_t)(N_NODES + B_GR * H_DIM) * sizeof(int), stream);

    k_linear<<<N_NODES / 8, 256, 0, stream>>>(x, Wl, Wr, xl, xr);
    k_hist  <<<N_EDGES / 4 / 256, 256, 0, stream>>>(ei + N_EDGES, cnt);
    k_scan_a<<<SCAN_NBLK, 256, 0, stream>>>(cnt, part, bsum);
    k_scan_b<<<1, 128, 0, stream>>>(bsum);
    k_scan_c<<<(N_NODES + 255) / 256, 256, 0, stream>>>(part, bsum, rowstart, cursor);
    k_build <<<N_BIN * BUILD_NBLK, 256, 0, stream>>>(ei, cursor, srt);
    k_aggregate<<<(size_t)N_NODES * 64 / 256, 256, 0, stream>>>(
        rowstart, srt, xl, xr, att, bias, batch, gu);
    k_mlp1<<<B_GR, 256, 0, stream>>>(gu, W1, b1, h1);
    k_mlp2<<<B_GR / 4, 512, 0, stream>>>(h1, W2, b2, h2);
    k_mlp3<<<B_GR, 256, 0, stream>>>(h2, W3, b3, out);
}